// Round 21
// baseline (152.141 us; speedup 1.0000x reference)
//
#include <hip/hip_runtime.h>

#define HW 3136
#define EPSV 1e-5f

typedef __attribute__((ext_vector_type(8))) short short8;
typedef __attribute__((ext_vector_type(4))) short short4_t;
typedef __attribute__((ext_vector_type(4))) float f32x4;

// ws byte offsets — NO ALIASING
#define OFF_OUT1BF 0u          // bf16 [b][px3136][ch256(perm)]  12,845,056 B
#define OFF_PART   25690112u   // f32 convgs partials [b][ch16][icc8][HW] = 12,845,056 B (dedicated)
#define OFF_WT1    51380224u   // bf16 [g][oc64][ic256(perm)]    131,072 B
#define OFF_WT2    51511296u   // bf16 [g][tap9][oc64][ic64(perm)] 294,912 B
#define OFF_WT3    51806208u   // bf16 [g][oc256][ic64(perm)]    131,072 B
#define OFF_SCSH   51937280u   // f32 sc1/sh1(256+256) sc2/sh2(256+256) sc3/sh3(1024+1024)
#define OFF_POOL   51949568u   // f32 8*16*49
#define OFF_MASKB  51974656u   // f32 8*4*49
// end: 51,980,928 bytes

#define OUT_ELEMS 25690112

__device__ __forceinline__ unsigned short f2b(float f) {
  union { float f; unsigned u; } v; v.f = f;
  unsigned r = v.u + 0x7fffu + ((v.u >> 16) & 1u);
  return (unsigned short)(r >> 16);
}

// k-order permutation within each 32-channel block:
// logical k-pair {l4*4+e, 16+l4*4+e} -> physical l4*8 + {e, 4+e} (contiguous 16B per fragment)
__device__ __forceinline__ int perm32i(int r) {
  int rr = r & 15;
  int p = ((rr >> 2) << 3) + (rr & 3);
  return (r & 16) ? (p + 4) : p;
}

// ---------------- prep: bf16 weights (k-permuted) + bn scale/shift ----------------
__global__ __launch_bounds__(256) void k_prep(const float* __restrict__ w1,
    const float* __restrict__ w2, const float* __restrict__ w3,
    const float* __restrict__ b1g, const float* __restrict__ b1b,
    const float* __restrict__ b1m, const float* __restrict__ b1v,
    const float* __restrict__ b2g, const float* __restrict__ b2b,
    const float* __restrict__ b2m, const float* __restrict__ b2v,
    const float* __restrict__ b3g, const float* __restrict__ b3b,
    const float* __restrict__ b3m, const float* __restrict__ b3v,
    char* __restrict__ wsb) {
  int i = blockIdx.x * 256 + threadIdx.x;
  short* wt1 = (short*)(wsb + OFF_WT1);
  short* wt2 = (short*)(wsb + OFF_WT2);
  short* wt3 = (short*)(wsb + OFF_WT3);
  float* sp  = (float*)(wsb + OFF_SCSH);
  if (i < 65536) {
    int ic = i & 255;
    int icp = (ic & ~31) | perm32i(ic & 31);
    wt1[(i & ~255) | icp] = (short)f2b(w1[i]);
  } else if (i < 65536 + 147456) {
    int j = i - 65536;
    int ic = j & 63, oc = (j >> 6) & 63, gt = j >> 12;  // gt = g*9 + t
    int g = gt / 9, t = gt - g * 9;
    int icp = (ic & 32) | perm32i(ic & 31);
    wt2[(j & ~63) | icp] = (short)f2b(w2[((size_t)((g * 64 + oc) * 64 + ic)) * 9 + t]);
  } else if (i < 278528) {
    int k = i - 212992;
    int ic = k & 63;
    int icp = (ic & 32) | perm32i(ic & 31);
    wt3[(k & ~63) | icp] = (short)f2b(w3[k]);
  } else if (i < 278528 + 1536) {
    int s = i - 278528;
    if (s < 256) {
      float sc = b1g[s] * rsqrtf(b1v[s] + EPSV);
      sp[s] = sc; sp[256 + s] = b1b[s] - b1m[s] * sc;
    } else if (s < 512) {
      int c = s - 256;
      float sc = b2g[c] * rsqrtf(b2v[c] + EPSV);
      sp[512 + c] = sc; sp[768 + c] = b2b[c] - b2m[c] * sc;
    } else {
      int c = s - 512;
      float sc = b3g[c] * rsqrtf(b3v[c] + EPSV);
      sp[1024 + c] = sc; sp[2048 + c] = b3b[c] - b3m[c] * sc;
    }
  }
}

// ---------------- maskGen conv partials: shuffle-based, icc8 split ----------------
// grid: b(8) x g(4) x rt(4) x icc(8) = 1024 blocks; 256 thr
__global__ __launch_bounds__(256) void k_convgs(const float* __restrict__ x,
    const float* __restrict__ w, char* __restrict__ wsb) {
  float* part = (float*)(wsb + OFF_PART);
  int blk = blockIdx.x;
  int icc = blk & 7, rt = (blk >> 3) & 3, g = (blk / 32) & 3, b = blk / 128;
  int tid = threadIdx.x;
  int wv = tid >> 6, lane = tid & 63;
  int qr = lane >> 4, qc = lane & 15;
  int y = rt * 16 + wv * 4 + qr;
  int c0 = qc * 4;
  int c0e = (qc < 14) ? c0 : 52;          // idle lanes: clamp address
  bool act = (qc < 14) && (y < 56);
  float acc[4][4];
  #pragma unroll
  for (int o = 0; o < 4; o++)
    #pragma unroll
    for (int p = 0; p < 4; p++) acc[o][p] = 0.f;
  const float* xb = x + (size_t)(b * 1024 + g * 256 + icc * 32) * HW;
  const float* wp = w + ((size_t)(g * 4) * 256 + icc * 32) * 9;
  #pragma unroll 4
  for (int ici = 0; ici < 32; ++ici) {
    const float* xr = xb + (size_t)ici * HW;
    #pragma unroll
    for (int dy = 0; dy < 3; dy++) {
      int row = y + dy - 1;
      float msk = ((unsigned)row < 56u) ? 1.f : 0.f;
      int rcl = row < 0 ? 0 : (row > 55 ? 55 : row);
      f32x4 m4 = *(const f32x4*)(xr + rcl * 56 + c0e);
      m4[0] *= msk; m4[1] *= msk; m4[2] *= msk; m4[3] *= msk;
      float lf = __shfl_up(m4[3], 1);
      float rg = __shfl_down(m4[0], 1);
      lf = (qc == 0) ? 0.f : lf;
      rg = (qc >= 13) ? 0.f : rg;
      float v[6] = {lf, m4[0], m4[1], m4[2], m4[3], rg};
      #pragma unroll
      for (int dx = 0; dx < 3; dx++) {
        #pragma unroll
        for (int oc = 0; oc < 4; oc++) {
          float wvt = wp[(size_t)oc * 2304 + ici * 9 + dy * 3 + dx];
          #pragma unroll
          for (int p = 0; p < 4; p++)
            acc[oc][p] = fmaf(wvt, v[dx + p], acc[oc][p]);
        }
      }
    }
  }
  if (act) {
    #pragma unroll
    for (int oc = 0; oc < 4; oc++) {
      f32x4 o4;
      o4[0] = acc[oc][0]; o4[1] = acc[oc][1]; o4[2] = acc[oc][2]; o4[3] = acc[oc][3];
      *(f32x4*)&part[((size_t)(b * 16 + g * 4 + oc) * 8 + icc) * HW + y * 56 + c0] = o4;
    }
  }
}

// ---------------- fused partial-reduce(8) + bn + relu + 8x8 avg pool ----------------
__global__ __launch_bounds__(256) void k_pool2(
    const float* __restrict__ bg, const float* __restrict__ bb,
    const float* __restrict__ bm, const float* __restrict__ bv,
    char* __restrict__ wsb) {
  const float* part = (const float*)(wsb + OFF_PART);
  float* pool = (float*)(wsb + OFF_POOL);
  int t = blockIdx.x * 256 + threadIdx.x;
  int lane = t & 63;
  int o = t >> 6;
  if (o >= 6272) return;
  int pw = o % 7, ph = (o / 7) % 7, ch = (o / 49) % 16, b = o / 784;
  int i = lane >> 3, j = lane & 7;
  int p = (ph * 8 + i) * 56 + (pw * 8 + j);
  const float* pp = part + (size_t)(b * 16 + ch) * 8 * HW + p;
  float s = 0.f;
  #pragma unroll
  for (int k = 0; k < 8; k++) s += pp[(size_t)k * HW];
  float sc = bg[ch] * rsqrtf(bv[ch] + EPSV);
  float sh = bb[ch] - bm[ch] * sc;
  float v = fmaxf(fmaf(s, sc, sh), 0.f);
  #pragma unroll
  for (int d = 32; d >= 1; d >>= 1) v += __shfl_xor(v, d, 64);
  if (lane == 0) pool[o] = v * (1.f / 64.f);
}

// ---------------- fc + gumbel hard argmax -> binary mask ----------------
__global__ __launch_bounds__(256) void k_mask(const float* __restrict__ gn,
    const float* __restrict__ fw, const float* __restrict__ fb,
    char* __restrict__ wsb, float* __restrict__ out_mask) {
  const float* pool = (const float*)(wsb + OFF_POOL);
  float* maskb = (float*)(wsb + OFF_MASKB);
  int t = blockIdx.x * 256 + threadIdx.x;
  if (t >= 8 * 4 * 49) return;
  int pw = t % 7, ph = (t / 7) % 7, g = (t / 49) & 3, b = t / 196;
  float s[2];
  #pragma unroll
  for (int i = 0; i < 2; i++) {
    int ci = i * 4 + g;
    int ib = (ci / 2) * 4;
    float l = fb[ci];
    #pragma unroll
    for (int k = 0; k < 4; k++)
      l = fmaf(fw[ci * 4 + k], pool[(size_t)(b * 16 + ib + k) * 49 + ph * 7 + pw], l);
    l += gn[((size_t)(b * 2 + i) * 4 + g) * 49 + ph * 7 + pw];
    s[i] = l;
  }
  float m = (s[1] > s[0]) ? 1.f : 0.f;
  maskb[t] = m;
  out_mask[t] = m;
}

// ---------------- conv1: MFMA, A = x direct, B = W1(perm) in LDS ----------------
// grid: 416 blocks (XCD-chunked remap), block 256 (4 waves x 64px each)
__global__ __launch_bounds__(256) void k_conv1(const float* __restrict__ x,
    char* __restrict__ wsb) {
  __shared__ short w1s[64 * 256];  // 32KB [oc][ic256(perm)], rows 512B, swz S=9
  int lb = (blockIdx.x & 7) * 52 + (blockIdx.x >> 3);   // XCD-chunked: 416 = 8*52
  int tile = lb % 13, g = (lb / 13) & 3, b = lb / 52;
  int px0 = tile * 256;
  int tid = threadIdx.x;
  const short* wt1 = (const short*)(wsb + OFF_WT1) + g * 16384;
  for (int u = tid; u < 2048; u += 256) {
    int byte = u * 16;
    short8 v = *(const short8*)((const char*)wt1 + byte);
    *(short8*)((char*)w1s + (byte ^ (((byte >> 9) & 7) << 4))) = v;
  }
  __syncthreads();
  int wv = tid >> 6, l = tid & 63, l15 = l & 15, l4 = l >> 4;
  int pxw = px0 + wv * 64;
  f32x4 acc[4][4];
  #pragma unroll
  for (int i = 0; i < 4; i++)
    #pragma unroll
    for (int j = 0; j < 4; j++) acc[i][j] = 0.f;
  const float* xg = x + (size_t)(b * 1024 + g * 256) * HW;
  int pxm[4];
  #pragma unroll
  for (int mf = 0; mf < 4; mf++) {
    int p = pxw + mf * 16 + l15;
    pxm[mf] = p < 3136 ? p : 3135;
  }
  for (int ks = 0; ks < 8; ks++) {
    int icb = ks * 32 + l4 * 4;
    short8 af[4];
    #pragma unroll
    for (int mf = 0; mf < 4; mf++) {
      const float* p = xg + (size_t)icb * HW + pxm[mf];
      float f0 = p[0], f1 = p[HW], f2 = p[2 * HW], f3 = p[3 * HW];
      const float* q = p + (size_t)16 * HW;
      float f4 = q[0], f5 = q[HW], f6 = q[2 * HW], f7 = q[3 * HW];
      short8 a;
      a[0] = (short)f2b(f0); a[1] = (short)f2b(f1); a[2] = (short)f2b(f2); a[3] = (short)f2b(f3);
      a[4] = (short)f2b(f4); a[5] = (short)f2b(f5); a[6] = (short)f2b(f6); a[7] = (short)f2b(f7);
      af[mf] = a;
    }
    short8 bf[4];
    #pragma unroll
    for (int nf = 0; nf < 4; nf++) {
      int byte = ((nf * 16 + l15) * 256 + ks * 32 + l4 * 8) * 2;
      bf[nf] = *(const short8*)((const char*)w1s + (byte ^ (((byte >> 9) & 7) << 4)));
    }
    #pragma unroll
    for (int mf = 0; mf < 4; mf++)
      #pragma unroll
      for (int nf = 0; nf < 4; nf++)
        acc[mf][nf] = __builtin_amdgcn_mfma_f32_16x16x32_bf16(af[mf], bf[nf], acc[mf][nf], 0, 0, 0);
  }
  const float* sc1 = (const float*)(wsb + OFF_SCSH);
  const float* sh1 = sc1 + 256;
  const float* maskb = (const float*)(wsb + OFF_MASKB);
  short* out1 = (short*)(wsb + OFF_OUT1BF);
  #pragma unroll
  for (int mf = 0; mf < 4; mf++) {
    #pragma unroll
    for (int reg = 0; reg < 4; reg++) {
      int px = pxw + mf * 16 + l4 * 4 + reg;
      if (px < 3136) {
        int py = px / 56, pc = px - py * 56;
        float m = maskb[((b * 4 + g) * 7 + (py >> 3)) * 7 + (pc >> 3)];
        size_t ob = (size_t)(b * 3136 + px) * 256 + g * 64;
        #pragma unroll
        for (int nf = 0; nf < 4; nf++) {
          int chl = nf * 16 + l15;
          int gch = g * 64 + chl;
          float v = fmaxf(acc[mf][nf][reg] * sc1[gch] + sh1[gch], 0.f) * m;
          int cph = (chl & 32) | perm32i(chl & 31);
          out1[ob + cph] = (short)f2b(v);
        }
      }
    }
  }
}

// ---------------- conv2+conv3 fused: conv2 -> out2 in LDS -> conv3 (all k-permuted) ----------------
// grid: 416 blocks (XCD-chunked remap), 256 thr
__global__ __launch_bounds__(256) void k_conv23(const float* __restrict__ x,
    char* __restrict__ wsb, float* __restrict__ out) {
  __shared__ short w2s[3 * 64 * 64];  // 24KB, 3 taps [tt][oc][ic64(perm)], rows 128B, swz S=7
  __shared__ short o2s[256 * 64];     // 32KB [pxlocal256][ic64(perm)], rows 128B, swz S=7
  int lb = (blockIdx.x & 7) * 52 + (blockIdx.x >> 3);   // XCD-chunked: 416 = 8*52
  int tile = lb % 13, g = (lb / 13) & 3, b = lb / 52;
  int px0 = tile * 256;
  int tid = threadIdx.x;
  int wv = tid >> 6, l = tid & 63, l15 = l & 15, l4 = l >> 4;
  // tail tile: zero o2s so phase-2 A-reads of invalid rows are defined
  if (tile == 12) {
    for (int u = tid; u < 2048; u += 256)
      *(short8*)((char*)o2s + u * 16) = short8{0,0,0,0,0,0,0,0};
  }
  // ---------- phase 1: conv2 ----------
  int pxw = px0 + wv * 64;
  int prow[4], pcol[4];
  #pragma unroll
  for (int mf = 0; mf < 4; mf++) {
    int p = pxw + mf * 16 + l15;
    if (p < 3136) { prow[mf] = p / 56; pcol[mf] = p - prow[mf] * 56; }
    else { prow[mf] = 1000; pcol[mf] = 0; }
  }
  f32x4 acc[4][4];
  #pragma unroll
  for (int i = 0; i < 4; i++)
    #pragma unroll
    for (int j = 0; j < 4; j++) acc[i][j] = 0.f;
  const short* o1 = (const short*)(wsb + OFF_OUT1BF) + (size_t)b * 3136 * 256 + g * 64;
  const short* wt2 = (const short*)(wsb + OFF_WT2) + (size_t)g * 36864;
  for (int tc = 0; tc < 3; tc++) {
    if (tc) __syncthreads();
    for (int u = tid; u < 1536; u += 256) {
      int byte = u * 16;
      short8 v = *(const short8*)((const char*)(wt2 + tc * 12288) + byte);
      *(short8*)((char*)w2s + (byte ^ (((byte >> 7) & 7) << 4))) = v;
    }
    __syncthreads();
    #pragma unroll
    for (int tt = 0; tt < 3; tt++) {
      int t = tc * 3 + tt;
      int dy = t / 3 - 1, dx = t % 3 - 1;
      int aok[4], pxe[4];
      #pragma unroll
      for (int mf = 0; mf < 4; mf++) {
        aok[mf] = ((unsigned)(prow[mf] + dy) < 56u) && ((unsigned)(pcol[mf] + dx) < 56u);
        pxe[mf] = (prow[mf] + dy) * 56 + (pcol[mf] + dx);
      }
      #pragma unroll
      for (int h = 0; h < 2; h++) {
        int icp = h * 32 + l4 * 8;          // permuted, contiguous 16B
        short8 af[4];
        #pragma unroll
        for (int mf = 0; mf < 4; mf++) {
          short8 a = {0, 0, 0, 0, 0, 0, 0, 0};
          if (aok[mf]) a = *(const short8*)(o1 + (size_t)pxe[mf] * 256 + icp);
          af[mf] = a;
        }
        short8 bf[4];
        #pragma unroll
        for (int nf = 0; nf < 4; nf++) {
          int byte = ((tt * 64 + nf * 16 + l15) * 64 + icp) * 2;
          bf[nf] = *(const short8*)((const char*)w2s + (byte ^ (((byte >> 7) & 7) << 4)));
        }
        #pragma unroll
        for (int mf = 0; mf < 4; mf++)
          #pragma unroll
          for (int nf = 0; nf < 4; nf++)
            acc[mf][nf] = __builtin_amdgcn_mfma_f32_16x16x32_bf16(af[mf], bf[nf], acc[mf][nf], 0, 0, 0);
      }
    }
  }
  {
    const float* sc2 = (const float*)(wsb + OFF_SCSH) + 512;
    const float* sh2 = (const float*)(wsb + OFF_SCSH) + 768;
    const float* maskb = (const float*)(wsb + OFF_MASKB);
    #pragma unroll
    for (int mf = 0; mf < 4; mf++) {
      #pragma unroll
      for (int reg = 0; reg < 4; reg++) {
        int px = pxw + mf * 16 + l4 * 4 + reg;
        if (px < 3136) {
          int py = px / 56, pc = px - py * 56;
          float m = maskb[((b * 4 + g) * 7 + (py >> 3)) * 7 + (pc >> 3)];
          int lr = wv * 64 + mf * 16 + l4 * 4 + reg;   // local row 0..255
          #pragma unroll
          for (int nf = 0; nf < 4; nf++) {
            int chl = nf * 16 + l15;
            int gch = g * 64 + chl;
            float v = fmaxf(acc[mf][nf][reg] * sc2[gch] + sh2[gch], 0.f) * m;
            int cph = (chl & 32) | perm32i(chl & 31);
            int byte = (lr * 64 + cph) * 2;
            *(short*)((char*)o2s + (byte ^ (((byte >> 7) & 7) << 4))) = (short)f2b(v);
          }
        }
      }
    }
  }
  __syncthreads();
  // ---------- phase 2: conv3 (px on M axis), 4 px-quarters; wt3 hoisted to regs ----------
  const short* wt3 = (const short*)(wsb + OFF_WT3) + g * 16384;
  const float* sc3 = (const float*)(wsb + OFF_SCSH) + 1024;
  const float* sh3 = (const float*)(wsb + OFF_SCSH) + 2048;
  int ocw = wv * 64;
  short8 bf3[2][4];
  #pragma unroll
  for (int h = 0; h < 2; h++) {
    int icp = h * 32 + l4 * 8;
    #pragma unroll
    for (int nf = 0; nf < 4; nf++)
      bf3[h][nf] = *(const short8*)(wt3 + (ocw + nf * 16 + l15) * 64 + icp);
  }
  for (int q = 0; q < 4; q++) {
    int pxq = px0 + q * 64;
    if (pxq >= 3136) break;                     // tail tile: only q=0 valid
    f32x4 acc3[4][4];
    #pragma unroll
    for (int i = 0; i < 4; i++)
      #pragma unroll
      for (int j = 0; j < 4; j++) acc3[i][j] = 0.f;
    #pragma unroll
    for (int h = 0; h < 2; h++) {
      int icp = h * 32 + l4 * 8;
      short8 af[4];
      #pragma unroll
      for (int mf = 0; mf < 4; mf++) {
        int lr = q * 64 + mf * 16 + l15;
        int byte = (lr * 64 + icp) * 2;
        af[mf] = *(const short8*)((const char*)o2s + (byte ^ (((byte >> 7) & 7) << 4)));
      }
      #pragma unroll
      for (int mf = 0; mf < 4; mf++)
        #pragma unroll
        for (int nf = 0; nf < 4; nf++)
          acc3[mf][nf] = __builtin_amdgcn_mfma_f32_16x16x32_bf16(af[mf], bf3[h][nf], acc3[mf][nf], 0, 0, 0);
    }
    #pragma unroll
    for (int nf = 0; nf < 4; nf++) {
      int gch = g * 256 + ocw + nf * 16 + l15;
      float sc = sc3[gch], sh = sh3[gch];
      size_t rowb = (size_t)(b * 1024 + gch) * HW + pxq;
      #pragma unroll
      for (int mf = 0; mf < 4; mf++) {
        int pxo = mf * 16 + l4 * 4;
        f32x4 xr = __builtin_nontemporal_load((const f32x4*)(x + rowb + pxo));
        f32x4 o;
        #pragma unroll
        for (int r = 0; r < 4; r++)
          o[r] = fmaxf(acc3[mf][nf][r] * sc + sh + xr[r], 0.f);
        __builtin_nontemporal_store(o, (f32x4*)(out + rowb + pxo));
      }
    }
  }
}

extern "C" void kernel_launch(void* const* d_in, const int* in_sizes, int n_in,
                              void* d_out, int out_size, void* d_ws, size_t ws_size,
                              hipStream_t stream) {
  const float* x     = (const float*)d_in[0];
  const float* gn    = (const float*)d_in[1];
  const float* wgs   = (const float*)d_in[2];
  const float* bgs_g = (const float*)d_in[3];
  const float* bgs_b = (const float*)d_in[4];
  const float* bgs_m = (const float*)d_in[5];
  const float* bgs_v = (const float*)d_in[6];
  const float* fw    = (const float*)d_in[7];
  const float* fb    = (const float*)d_in[8];
  const float* w1    = (const float*)d_in[9];
  const float* bn1g  = (const float*)d_in[10];
  const float* bn1b  = (const float*)d_in[11];
  const float* bn1m  = (const float*)d_in[12];
  const float* bn1v  = (const float*)d_in[13];
  const float* w2    = (const float*)d_in[14];
  const float* bn2g  = (const float*)d_in[15];
  const float* bn2b  = (const float*)d_in[16];
  const float* bn2m  = (const float*)d_in[17];
  const float* bn2v  = (const float*)d_in[18];
  const float* w3    = (const float*)d_in[19];
  const float* bn3g  = (const float*)d_in[20];
  const float* bn3b  = (const float*)d_in[21];
  const float* bn3m  = (const float*)d_in[22];
  const float* bn3v  = (const float*)d_in[23];

  float* out = (float*)d_out;
  char* wsb  = (char*)d_ws;
  float* mask_out = out + OUT_ELEMS;

  k_prep  <<<1095, 256, 0, stream>>>(w1, w2, w3, bn1g, bn1b, bn1m, bn1v,
                                     bn2g, bn2b, bn2m, bn2v, bn3g, bn3b, bn3m, bn3v, wsb);
  k_convgs<<<1024, 256, 0, stream>>>(x, wgs, wsb);
  k_pool2 <<<1568, 256, 0, stream>>>(bgs_g, bgs_b, bgs_m, bgs_v, wsb);
  k_mask  <<<7,    256, 0, stream>>>(gn, fw, fb, wsb, mask_out);
  k_conv1 <<<416,  256, 0, stream>>>(x, wsb);
  k_conv23<<<416,  256, 0, stream>>>(x, wsb, out);
}

// Round 22
// 128.875 us; speedup vs baseline: 1.1805x; 1.1805x over previous
//
#include <hip/hip_runtime.h>

#define HW 3136
#define EPSV 1e-5f

typedef __attribute__((ext_vector_type(8))) short short8;
typedef __attribute__((ext_vector_type(4))) short short4_t;
typedef __attribute__((ext_vector_type(4))) float f32x4;

// ws byte offsets — NO ALIASING
#define OFF_OUT1BF 0u          // bf16 [b][px3136][ch256(perm)]  12,845,056 B
#define OFF_PART   25690112u   // f32 convgs partials [b][ch16][icc8][HW] = 12,845,056 B (dedicated)
#define OFF_WT1    51380224u   // bf16 [g][oc64][ic256(perm)]    131,072 B
#define OFF_WT2    51511296u   // bf16 [g][tap9][oc64][ic64(perm)] 294,912 B
#define OFF_WT3    51806208u   // bf16 [g][oc256][ic64(perm)]    131,072 B
#define OFF_SCSH   51937280u   // f32 sc1/sh1(256+256) sc2/sh2(256+256) sc3/sh3(1024+1024)
#define OFF_POOL   51949568u   // f32 8*16*49
#define OFF_MASKB  51974656u   // f32 8*4*49
// end: 51,980,928 bytes

#define OUT_ELEMS 25690112

__device__ __forceinline__ unsigned short f2b(float f) {
  union { float f; unsigned u; } v; v.f = f;
  unsigned r = v.u + 0x7fffu + ((v.u >> 16) & 1u);
  return (unsigned short)(r >> 16);
}

// k-order permutation within each 32-channel block:
// logical k-pair {l4*4+e, 16+l4*4+e} -> physical l4*8 + {e, 4+e} (contiguous 16B per fragment)
__device__ __forceinline__ int perm32i(int r) {
  int rr = r & 15;
  int p = ((rr >> 2) << 3) + (rr & 3);
  return (r & 16) ? (p + 4) : p;
}

// ---------------- prep: bf16 weights (k-permuted) + bn scale/shift ----------------
__global__ __launch_bounds__(256) void k_prep(const float* __restrict__ w1,
    const float* __restrict__ w2, const float* __restrict__ w3,
    const float* __restrict__ b1g, const float* __restrict__ b1b,
    const float* __restrict__ b1m, const float* __restrict__ b1v,
    const float* __restrict__ b2g, const float* __restrict__ b2b,
    const float* __restrict__ b2m, const float* __restrict__ b2v,
    const float* __restrict__ b3g, const float* __restrict__ b3b,
    const float* __restrict__ b3m, const float* __restrict__ b3v,
    char* __restrict__ wsb) {
  int i = blockIdx.x * 256 + threadIdx.x;
  short* wt1 = (short*)(wsb + OFF_WT1);
  short* wt2 = (short*)(wsb + OFF_WT2);
  short* wt3 = (short*)(wsb + OFF_WT3);
  float* sp  = (float*)(wsb + OFF_SCSH);
  if (i < 65536) {
    int ic = i & 255;
    int icp = (ic & ~31) | perm32i(ic & 31);
    wt1[(i & ~255) | icp] = (short)f2b(w1[i]);
  } else if (i < 65536 + 147456) {
    int j = i - 65536;
    int ic = j & 63, oc = (j >> 6) & 63, gt = j >> 12;  // gt = g*9 + t
    int g = gt / 9, t = gt - g * 9;
    int icp = (ic & 32) | perm32i(ic & 31);
    wt2[(j & ~63) | icp] = (short)f2b(w2[((size_t)((g * 64 + oc) * 64 + ic)) * 9 + t]);
  } else if (i < 278528) {
    int k = i - 212992;
    int ic = k & 63;
    int icp = (ic & 32) | perm32i(ic & 31);
    wt3[(k & ~63) | icp] = (short)f2b(w3[k]);
  } else if (i < 278528 + 1536) {
    int s = i - 278528;
    if (s < 256) {
      float sc = b1g[s] * rsqrtf(b1v[s] + EPSV);
      sp[s] = sc; sp[256 + s] = b1b[s] - b1m[s] * sc;
    } else if (s < 512) {
      int c = s - 256;
      float sc = b2g[c] * rsqrtf(b2v[c] + EPSV);
      sp[512 + c] = sc; sp[768 + c] = b2b[c] - b2m[c] * sc;
    } else {
      int c = s - 512;
      float sc = b3g[c] * rsqrtf(b3v[c] + EPSV);
      sp[1024 + c] = sc; sp[2048 + c] = b3b[c] - b3m[c] * sc;
    }
  }
}

// ---------------- maskGen conv partials: shuffle-based, icc8 split ----------------
// grid: b(8) x g(4) x rt(4) x icc(8) = 1024 blocks; 256 thr
__global__ __launch_bounds__(256) void k_convgs(const float* __restrict__ x,
    const float* __restrict__ w, char* __restrict__ wsb) {
  float* part = (float*)(wsb + OFF_PART);
  int blk = blockIdx.x;
  int icc = blk & 7, rt = (blk >> 3) & 3, g = (blk / 32) & 3, b = blk / 128;
  int tid = threadIdx.x;
  int wv = tid >> 6, lane = tid & 63;
  int qr = lane >> 4, qc = lane & 15;
  int y = rt * 16 + wv * 4 + qr;
  int c0 = qc * 4;
  int c0e = (qc < 14) ? c0 : 52;          // idle lanes: clamp address
  bool act = (qc < 14) && (y < 56);
  float acc[4][4];
  #pragma unroll
  for (int o = 0; o < 4; o++)
    #pragma unroll
    for (int p = 0; p < 4; p++) acc[o][p] = 0.f;
  const float* xb = x + (size_t)(b * 1024 + g * 256 + icc * 32) * HW;
  const float* wp = w + ((size_t)(g * 4) * 256 + icc * 32) * 9;
  #pragma unroll 4
  for (int ici = 0; ici < 32; ++ici) {
    const float* xr = xb + (size_t)ici * HW;
    #pragma unroll
    for (int dy = 0; dy < 3; dy++) {
      int row = y + dy - 1;
      float msk = ((unsigned)row < 56u) ? 1.f : 0.f;
      int rcl = row < 0 ? 0 : (row > 55 ? 55 : row);
      f32x4 m4 = *(const f32x4*)(xr + rcl * 56 + c0e);
      m4[0] *= msk; m4[1] *= msk; m4[2] *= msk; m4[3] *= msk;
      float lf = __shfl_up(m4[3], 1);
      float rg = __shfl_down(m4[0], 1);
      lf = (qc == 0) ? 0.f : lf;
      rg = (qc >= 13) ? 0.f : rg;
      float v[6] = {lf, m4[0], m4[1], m4[2], m4[3], rg};
      #pragma unroll
      for (int dx = 0; dx < 3; dx++) {
        #pragma unroll
        for (int oc = 0; oc < 4; oc++) {
          float wvt = wp[(size_t)oc * 2304 + ici * 9 + dy * 3 + dx];
          #pragma unroll
          for (int p = 0; p < 4; p++)
            acc[oc][p] = fmaf(wvt, v[dx + p], acc[oc][p]);
        }
      }
    }
  }
  if (act) {
    #pragma unroll
    for (int oc = 0; oc < 4; oc++) {
      f32x4 o4;
      o4[0] = acc[oc][0]; o4[1] = acc[oc][1]; o4[2] = acc[oc][2]; o4[3] = acc[oc][3];
      *(f32x4*)&part[((size_t)(b * 16 + g * 4 + oc) * 8 + icc) * HW + y * 56 + c0] = o4;
    }
  }
}

// ---------------- fused partial-reduce(8) + bn + relu + 8x8 avg pool ----------------
__global__ __launch_bounds__(256) void k_pool2(
    const float* __restrict__ bg, const float* __restrict__ bb,
    const float* __restrict__ bm, const float* __restrict__ bv,
    char* __restrict__ wsb) {
  const float* part = (const float*)(wsb + OFF_PART);
  float* pool = (float*)(wsb + OFF_POOL);
  int t = blockIdx.x * 256 + threadIdx.x;
  int lane = t & 63;
  int o = t >> 6;
  if (o >= 6272) return;
  int pw = o % 7, ph = (o / 7) % 7, ch = (o / 49) % 16, b = o / 784;
  int i = lane >> 3, j = lane & 7;
  int p = (ph * 8 + i) * 56 + (pw * 8 + j);
  const float* pp = part + (size_t)(b * 16 + ch) * 8 * HW + p;
  float s = 0.f;
  #pragma unroll
  for (int k = 0; k < 8; k++) s += pp[(size_t)k * HW];
  float sc = bg[ch] * rsqrtf(bv[ch] + EPSV);
  float sh = bb[ch] - bm[ch] * sc;
  float v = fmaxf(fmaf(s, sc, sh), 0.f);
  #pragma unroll
  for (int d = 32; d >= 1; d >>= 1) v += __shfl_xor(v, d, 64);
  if (lane == 0) pool[o] = v * (1.f / 64.f);
}

// ---------------- fc + gumbel hard argmax -> binary mask ----------------
__global__ __launch_bounds__(256) void k_mask(const float* __restrict__ gn,
    const float* __restrict__ fw, const float* __restrict__ fb,
    char* __restrict__ wsb, float* __restrict__ out_mask) {
  const float* pool = (const float*)(wsb + OFF_POOL);
  float* maskb = (float*)(wsb + OFF_MASKB);
  int t = blockIdx.x * 256 + threadIdx.x;
  if (t >= 8 * 4 * 49) return;
  int pw = t % 7, ph = (t / 7) % 7, g = (t / 49) & 3, b = t / 196;
  float s[2];
  #pragma unroll
  for (int i = 0; i < 2; i++) {
    int ci = i * 4 + g;
    int ib = (ci / 2) * 4;
    float l = fb[ci];
    #pragma unroll
    for (int k = 0; k < 4; k++)
      l = fmaf(fw[ci * 4 + k], pool[(size_t)(b * 16 + ib + k) * 49 + ph * 7 + pw], l);
    l += gn[((size_t)(b * 2 + i) * 4 + g) * 49 + ph * 7 + pw];
    s[i] = l;
  }
  float m = (s[1] > s[0]) ? 1.f : 0.f;
  maskb[t] = m;
  out_mask[t] = m;
}

// ---------------- conv1: MFMA, A = x direct, B = W1(perm) in LDS ----------------
// grid: b(8) x g(4) x pxtile(13), block 256 (4 waves x 64px each)
__global__ __launch_bounds__(256) void k_conv1(const float* __restrict__ x,
    char* __restrict__ wsb) {
  __shared__ short w1s[64 * 256];  // 32KB [oc][ic256(perm)], rows 512B, swz S=9
  int blk = blockIdx.x;
  int tile = blk % 13, g = (blk / 13) & 3, b = blk / 52;
  int px0 = tile * 256;
  int tid = threadIdx.x;
  const short* wt1 = (const short*)(wsb + OFF_WT1) + g * 16384;
  for (int u = tid; u < 2048; u += 256) {
    int byte = u * 16;
    short8 v = *(const short8*)((const char*)wt1 + byte);
    *(short8*)((char*)w1s + (byte ^ (((byte >> 9) & 7) << 4))) = v;
  }
  __syncthreads();
  int wv = tid >> 6, l = tid & 63, l15 = l & 15, l4 = l >> 4;
  int pxw = px0 + wv * 64;
  f32x4 acc[4][4];
  #pragma unroll
  for (int i = 0; i < 4; i++)
    #pragma unroll
    for (int j = 0; j < 4; j++) acc[i][j] = 0.f;
  const float* xg = x + (size_t)(b * 1024 + g * 256) * HW;
  int pxm[4];
  #pragma unroll
  for (int mf = 0; mf < 4; mf++) {
    int p = pxw + mf * 16 + l15;
    pxm[mf] = p < 3136 ? p : 3135;
  }
  for (int ks = 0; ks < 8; ks++) {
    int icb = ks * 32 + l4 * 4;
    short8 af[4];
    #pragma unroll
    for (int mf = 0; mf < 4; mf++) {
      const float* p = xg + (size_t)icb * HW + pxm[mf];
      float f0 = p[0], f1 = p[HW], f2 = p[2 * HW], f3 = p[3 * HW];
      const float* q = p + (size_t)16 * HW;
      float f4 = q[0], f5 = q[HW], f6 = q[2 * HW], f7 = q[3 * HW];
      short8 a;
      a[0] = (short)f2b(f0); a[1] = (short)f2b(f1); a[2] = (short)f2b(f2); a[3] = (short)f2b(f3);
      a[4] = (short)f2b(f4); a[5] = (short)f2b(f5); a[6] = (short)f2b(f6); a[7] = (short)f2b(f7);
      af[mf] = a;
    }
    short8 bf[4];
    #pragma unroll
    for (int nf = 0; nf < 4; nf++) {
      int byte = ((nf * 16 + l15) * 256 + ks * 32 + l4 * 8) * 2;
      bf[nf] = *(const short8*)((const char*)w1s + (byte ^ (((byte >> 9) & 7) << 4)));
    }
    #pragma unroll
    for (int mf = 0; mf < 4; mf++)
      #pragma unroll
      for (int nf = 0; nf < 4; nf++)
        acc[mf][nf] = __builtin_amdgcn_mfma_f32_16x16x32_bf16(af[mf], bf[nf], acc[mf][nf], 0, 0, 0);
  }
  const float* sc1 = (const float*)(wsb + OFF_SCSH);
  const float* sh1 = sc1 + 256;
  const float* maskb = (const float*)(wsb + OFF_MASKB);
  short* out1 = (short*)(wsb + OFF_OUT1BF);
  #pragma unroll
  for (int mf = 0; mf < 4; mf++) {
    #pragma unroll
    for (int reg = 0; reg < 4; reg++) {
      int px = pxw + mf * 16 + l4 * 4 + reg;
      if (px < 3136) {
        int py = px / 56, pc = px - py * 56;
        float m = maskb[((b * 4 + g) * 7 + (py >> 3)) * 7 + (pc >> 3)];
        size_t ob = (size_t)(b * 3136 + px) * 256 + g * 64;
        #pragma unroll
        for (int nf = 0; nf < 4; nf++) {
          int chl = nf * 16 + l15;
          int gch = g * 64 + chl;
          float v = fmaxf(acc[mf][nf][reg] * sc1[gch] + sh1[gch], 0.f) * m;
          int cph = (chl & 32) | perm32i(chl & 31);
          out1[ob + cph] = (short)f2b(v);
        }
      }
    }
  }
}

// ---------------- conv2+conv3 fused: conv2 -> out2 in LDS -> conv3 (all k-permuted) ----------------
// grid: b(8) x g(4) x pxtile(13) = 416 blocks, 256 thr
__global__ __launch_bounds__(256) void k_conv23(const float* __restrict__ x,
    char* __restrict__ wsb, float* __restrict__ out) {
  __shared__ short w2s[3 * 64 * 64];  // 24KB, 3 taps [tt][oc][ic64(perm)], rows 128B, swz S=7
  __shared__ short o2s[256 * 64];     // 32KB [pxlocal256][ic64(perm)], rows 128B, swz S=7
  int blk = blockIdx.x;
  int tile = blk % 13, g = (blk / 13) & 3, b = blk / 52;
  int px0 = tile * 256;
  int tid = threadIdx.x;
  int wv = tid >> 6, l = tid & 63, l15 = l & 15, l4 = l >> 4;
  // tail tile: zero o2s so phase-2 A-reads of invalid rows are defined
  if (tile == 12) {
    for (int u = tid; u < 2048; u += 256)
      *(short8*)((char*)o2s + u * 16) = short8{0,0,0,0,0,0,0,0};
  }
  // ---------- phase 1: conv2 ----------
  int pxw = px0 + wv * 64;
  int prow[4], pcol[4];
  #pragma unroll
  for (int mf = 0; mf < 4; mf++) {
    int p = pxw + mf * 16 + l15;
    if (p < 3136) { prow[mf] = p / 56; pcol[mf] = p - prow[mf] * 56; }
    else { prow[mf] = 1000; pcol[mf] = 0; }
  }
  f32x4 acc[4][4];
  #pragma unroll
  for (int i = 0; i < 4; i++)
    #pragma unroll
    for (int j = 0; j < 4; j++) acc[i][j] = 0.f;
  const short* o1 = (const short*)(wsb + OFF_OUT1BF) + (size_t)b * 3136 * 256 + g * 64;
  const short* wt2 = (const short*)(wsb + OFF_WT2) + (size_t)g * 36864;
  for (int tc = 0; tc < 3; tc++) {
    if (tc) __syncthreads();
    for (int u = tid; u < 1536; u += 256) {
      int byte = u * 16;
      short8 v = *(const short8*)((const char*)(wt2 + tc * 12288) + byte);
      *(short8*)((char*)w2s + (byte ^ (((byte >> 7) & 7) << 4))) = v;
    }
    __syncthreads();
    #pragma unroll
    for (int tt = 0; tt < 3; tt++) {
      int t = tc * 3 + tt;
      int dy = t / 3 - 1, dx = t % 3 - 1;
      int aok[4], pxe[4];
      #pragma unroll
      for (int mf = 0; mf < 4; mf++) {
        aok[mf] = ((unsigned)(prow[mf] + dy) < 56u) && ((unsigned)(pcol[mf] + dx) < 56u);
        pxe[mf] = (prow[mf] + dy) * 56 + (pcol[mf] + dx);
      }
      #pragma unroll
      for (int h = 0; h < 2; h++) {
        int icp = h * 32 + l4 * 8;          // permuted, contiguous 16B
        short8 af[4];
        #pragma unroll
        for (int mf = 0; mf < 4; mf++) {
          short8 a = {0, 0, 0, 0, 0, 0, 0, 0};
          if (aok[mf]) a = *(const short8*)(o1 + (size_t)pxe[mf] * 256 + icp);
          af[mf] = a;
        }
        short8 bf[4];
        #pragma unroll
        for (int nf = 0; nf < 4; nf++) {
          int byte = ((tt * 64 + nf * 16 + l15) * 64 + icp) * 2;
          bf[nf] = *(const short8*)((const char*)w2s + (byte ^ (((byte >> 7) & 7) << 4)));
        }
        #pragma unroll
        for (int mf = 0; mf < 4; mf++)
          #pragma unroll
          for (int nf = 0; nf < 4; nf++)
            acc[mf][nf] = __builtin_amdgcn_mfma_f32_16x16x32_bf16(af[mf], bf[nf], acc[mf][nf], 0, 0, 0);
      }
    }
  }
  {
    const float* sc2 = (const float*)(wsb + OFF_SCSH) + 512;
    const float* sh2 = (const float*)(wsb + OFF_SCSH) + 768;
    const float* maskb = (const float*)(wsb + OFF_MASKB);
    #pragma unroll
    for (int mf = 0; mf < 4; mf++) {
      #pragma unroll
      for (int reg = 0; reg < 4; reg++) {
        int px = pxw + mf * 16 + l4 * 4 + reg;
        if (px < 3136) {
          int py = px / 56, pc = px - py * 56;
          float m = maskb[((b * 4 + g) * 7 + (py >> 3)) * 7 + (pc >> 3)];
          int lr = wv * 64 + mf * 16 + l4 * 4 + reg;   // local row 0..255
          #pragma unroll
          for (int nf = 0; nf < 4; nf++) {
            int chl = nf * 16 + l15;
            int gch = g * 64 + chl;
            float v = fmaxf(acc[mf][nf][reg] * sc2[gch] + sh2[gch], 0.f) * m;
            int cph = (chl & 32) | perm32i(chl & 31);
            int byte = (lr * 64 + cph) * 2;
            *(short*)((char*)o2s + (byte ^ (((byte >> 7) & 7) << 4))) = (short)f2b(v);
          }
        }
      }
    }
  }
  __syncthreads();
  // ---------- phase 2: conv3 (px on M axis), 4 px-quarters; wt3 hoisted to regs ----------
  const short* wt3 = (const short*)(wsb + OFF_WT3) + g * 16384;
  const float* sc3 = (const float*)(wsb + OFF_SCSH) + 1024;
  const float* sh3 = (const float*)(wsb + OFF_SCSH) + 2048;
  int ocw = wv * 64;
  short8 bf3[2][4];
  #pragma unroll
  for (int h = 0; h < 2; h++) {
    int icp = h * 32 + l4 * 8;
    #pragma unroll
    for (int nf = 0; nf < 4; nf++)
      bf3[h][nf] = *(const short8*)(wt3 + (ocw + nf * 16 + l15) * 64 + icp);
  }
  for (int q = 0; q < 4; q++) {
    int pxq = px0 + q * 64;
    if (pxq >= 3136) break;                     // tail tile: only q=0 valid
    f32x4 acc3[4][4];
    #pragma unroll
    for (int i = 0; i < 4; i++)
      #pragma unroll
      for (int j = 0; j < 4; j++) acc3[i][j] = 0.f;
    #pragma unroll
    for (int h = 0; h < 2; h++) {
      int icp = h * 32 + l4 * 8;
      short8 af[4];
      #pragma unroll
      for (int mf = 0; mf < 4; mf++) {
        int lr = q * 64 + mf * 16 + l15;
        int byte = (lr * 64 + icp) * 2;
        af[mf] = *(const short8*)((const char*)o2s + (byte ^ (((byte >> 7) & 7) << 4)));
      }
      #pragma unroll
      for (int mf = 0; mf < 4; mf++)
        #pragma unroll
        for (int nf = 0; nf < 4; nf++)
          acc3[mf][nf] = __builtin_amdgcn_mfma_f32_16x16x32_bf16(af[mf], bf3[h][nf], acc3[mf][nf], 0, 0, 0);
    }
    #pragma unroll
    for (int nf = 0; nf < 4; nf++) {
      int gch = g * 256 + ocw + nf * 16 + l15;
      float sc = sc3[gch], sh = sh3[gch];
      size_t rowb = (size_t)(b * 1024 + gch) * HW + pxq;
      #pragma unroll
      for (int mf = 0; mf < 4; mf++) {
        int pxo = mf * 16 + l4 * 4;
        f32x4 xr = *(const f32x4*)(x + rowb + pxo);
        f32x4 o;
        #pragma unroll
        for (int r = 0; r < 4; r++)
          o[r] = fmaxf(acc3[mf][nf][r] * sc + sh + xr[r], 0.f);
        *(f32x4*)(out + rowb + pxo) = o;
      }
    }
  }
}

extern "C" void kernel_launch(void* const* d_in, const int* in_sizes, int n_in,
                              void* d_out, int out_size, void* d_ws, size_t ws_size,
                              hipStream_t stream) {
  const float* x     = (const float*)d_in[0];
  const float* gn    = (const float*)d_in[1];
  const float* wgs   = (const float*)d_in[2];
  const float* bgs_g = (const float*)d_in[3];
  const float* bgs_b = (const float*)d_in[4];
  const float* bgs_m = (const float*)d_in[5];
  const float* bgs_v = (const float*)d_in[6];
  const float* fw    = (const float*)d_in[7];
  const float* fb    = (const float*)d_in[8];
  const float* w1    = (const float*)d_in[9];
  const float* bn1g  = (const float*)d_in[10];
  const float* bn1b  = (const float*)d_in[11];
  const float* bn1m  = (const float*)d_in[12];
  const float* bn1v  = (const float*)d_in[13];
  const float* w2    = (const float*)d_in[14];
  const float* bn2g  = (const float*)d_in[15];
  const float* bn2b  = (const float*)d_in[16];
  const float* bn2m  = (const float*)d_in[17];
  const float* bn2v  = (const float*)d_in[18];
  const float* w3    = (const float*)d_in[19];
  const float* bn3g  = (const float*)d_in[20];
  const float* bn3b  = (const float*)d_in[21];
  const float* bn3m  = (const float*)d_in[22];
  const float* bn3v  = (const float*)d_in[23];

  float* out = (float*)d_out;
  char* wsb  = (char*)d_ws;
  float* mask_out = out + OUT_ELEMS;

  k_prep  <<<1095, 256, 0, stream>>>(w1, w2, w3, bn1g, bn1b, bn1m, bn1v,
                                     bn2g, bn2b, bn2m, bn2v, bn3g, bn3b, bn3m, bn3v, wsb);
  k_convgs<<<1024, 256, 0, stream>>>(x, wgs, wsb);
  k_pool2 <<<1568, 256, 0, stream>>>(bgs_g, bgs_b, bgs_m, bgs_v, wsb);
  k_mask  <<<7,    256, 0, stream>>>(gn, fw, fb, wsb, mask_out);
  k_conv1 <<<416,  256, 0, stream>>>(x, wsb);
  k_conv23<<<416,  256, 0, stream>>>(x, wsb, out);
}